// Round 1
// baseline (1129.665 us; speedup 1.0000x reference)
//
#include <hip/hip_runtime.h>

#define HIDDEN 128

// 32 threads per edge; each thread gathers a float4 (16B) of the node's
// feature row and scatter-adds it into the hyperedge's accumulator row.
__global__ void scatter_add_kernel(const float* __restrict__ node_feats,
                                   const int* __restrict__ he_index,  // [2, E] flat
                                   float* __restrict__ out_sums,      // [num_he, HIDDEN]
                                   float* __restrict__ counts,        // [num_he]
                                   int E) {
    int tid  = blockIdx.x * blockDim.x + threadIdx.x;
    int edge = tid >> 5;
    int lane = tid & 31;
    if (edge >= E) return;

    int node = he_index[edge];       // row 0: node indices
    int he   = he_index[E + edge];   // row 1: hyperedge indices

    const float4* src =
        reinterpret_cast<const float4*>(node_feats + (size_t)node * HIDDEN);
    float4 v = src[lane];

    float* dst = out_sums + (size_t)he * HIDDEN + (size_t)lane * 4;
    atomicAdd(dst + 0, v.x);
    atomicAdd(dst + 1, v.y);
    atomicAdd(dst + 2, v.z);
    atomicAdd(dst + 3, v.w);

    if (lane == 0) atomicAdd(counts + he, 1.0f);
}

// One thread per (hyperedge, 4-float chunk): out = sums / max(count, 1)
__global__ void finalize_kernel(float* __restrict__ out,
                                const float* __restrict__ counts,
                                int num_he) {
    int tid = blockIdx.x * blockDim.x + threadIdx.x;
    int total = num_he * (HIDDEN / 4);
    if (tid >= total) return;

    int he = tid >> 5;                 // HIDDEN/4 == 32 chunks per hyperedge
    float c = fmaxf(counts[he], 1.0f);

    float4* p = reinterpret_cast<float4*>(out) + tid;
    float4 v = *p;
    v.x /= c;
    v.y /= c;
    v.z /= c;
    v.w /= c;
    *p = v;
}

extern "C" void kernel_launch(void* const* d_in, const int* in_sizes, int n_in,
                              void* d_out, int out_size, void* d_ws, size_t ws_size,
                              hipStream_t stream) {
    const float* node_feats = (const float*)d_in[0];
    const int* he_index     = (const int*)d_in[1];
    float* out              = (float*)d_out;
    float* counts           = (float*)d_ws;

    const int E      = in_sizes[1] / 2;      // 600000
    const int num_he = out_size / HIDDEN;    // 50000

    // Zero the accumulators (d_out / d_ws are poisoned with 0xAA each call).
    hipMemsetAsync(d_out, 0, (size_t)out_size * sizeof(float), stream);
    hipMemsetAsync(d_ws, 0, (size_t)num_he * sizeof(float), stream);

    // Scatter: 32 threads per edge.
    {
        const int threads = 256;
        const long long total = (long long)E * 32;
        const int blocks = (int)((total + threads - 1) / threads);
        scatter_add_kernel<<<blocks, threads, 0, stream>>>(
            node_feats, he_index, out, counts, E);
    }

    // Finalize: divide by clamped counts.
    {
        const int threads = 256;
        const int total = num_he * (HIDDEN / 4);
        const int blocks = (total + threads - 1) / threads;
        finalize_kernel<<<blocks, threads, 0, stream>>>(out, counts, num_he);
    }
}

// Round 2
// 298.976 us; speedup vs baseline: 3.7785x; 3.7785x over previous
//
#include <hip/hip_runtime.h>

#define HIDDEN 128

// ---------------------------------------------------------------------------
// Phase 1: histogram of hyperedge degrees (int atomics on L2-resident array)
// ---------------------------------------------------------------------------
__global__ void hist_kernel(const int* __restrict__ he_index,  // [2, E] flat
                            int* __restrict__ counts,          // [num_he]
                            int E) {
    int e = blockIdx.x * blockDim.x + threadIdx.x;
    if (e >= E) return;
    atomicAdd(&counts[he_index[E + e]], 1);
}

// ---------------------------------------------------------------------------
// Phase 2: single-workgroup exclusive prefix sum over counts -> offsets,
// and a second copy in `cursor` for the placement pass.
// 1024 threads, each serially scans a contiguous chunk; one LDS scan of the
// 1024 chunk-sums (~20 syncthreads total).
// ---------------------------------------------------------------------------
__global__ void scan_kernel(const int* __restrict__ counts,
                            int* __restrict__ offsets,  // [num_he + 1]
                            int* __restrict__ cursor,   // [num_he]
                            int num_he) {
    const int T = 1024;
    int chunk = (num_he + T - 1) / T;
    int begin = threadIdx.x * chunk;
    int end   = begin + chunk;
    if (end > num_he) end = num_he;
    if (begin > num_he) begin = num_he;

    int sum = 0;
    for (int i = begin; i < end; ++i) sum += counts[i];

    __shared__ int lds[T];
    lds[threadIdx.x] = sum;
    __syncthreads();
    for (int off = 1; off < T; off <<= 1) {
        int t = (threadIdx.x >= off) ? lds[threadIdx.x - off] : 0;
        __syncthreads();
        lds[threadIdx.x] += t;
        __syncthreads();
    }
    int run = lds[threadIdx.x] - sum;  // exclusive prefix of this chunk

    for (int i = begin; i < end; ++i) {
        offsets[i] = run;
        cursor[i]  = run;
        run += counts[i];
    }
    if (threadIdx.x == T - 1) offsets[num_he] = lds[T - 1];  // grand total = E
}

// ---------------------------------------------------------------------------
// Phase 3: place node indices into CSR order (int atomics for slots)
// ---------------------------------------------------------------------------
__global__ void place_kernel(const int* __restrict__ he_index,   // [2, E]
                             int* __restrict__ cursor,           // [num_he]
                             int* __restrict__ sorted_node,      // [E]
                             int E) {
    int e = blockIdx.x * blockDim.x + threadIdx.x;
    if (e >= E) return;
    int node = he_index[e];
    int he   = he_index[E + e];
    int pos  = atomicAdd(&cursor[he], 1);
    sorted_node[pos] = node;
}

// ---------------------------------------------------------------------------
// Phase 4: one wave (64 lanes) per hyperedge; lane l accumulates floats
// [2l, 2l+1] across the member nodes, then writes once. No atomics.
// ---------------------------------------------------------------------------
__global__ void aggregate_kernel(const float* __restrict__ node_feats,
                                 const int* __restrict__ offsets,
                                 const int* __restrict__ sorted_node,
                                 float* __restrict__ out,
                                 int num_he) {
    int gtid = blockIdx.x * blockDim.x + threadIdx.x;
    int wave = gtid >> 6;
    int lane = threadIdx.x & 63;
    if (wave >= num_he) return;

    int start = offsets[wave];
    int end   = offsets[wave + 1];

    float ax = 0.f, ay = 0.f, bx = 0.f, by = 0.f;
    int j = start;
    // 2-way unroll: two independent gathers in flight, two accumulator pairs
    for (; j + 1 < end; j += 2) {
        int n0 = sorted_node[j];
        int n1 = sorted_node[j + 1];
        float2 v0 = reinterpret_cast<const float2*>(
                        node_feats + (size_t)n0 * HIDDEN)[lane];
        float2 v1 = reinterpret_cast<const float2*>(
                        node_feats + (size_t)n1 * HIDDEN)[lane];
        ax += v0.x; ay += v0.y;
        bx += v1.x; by += v1.y;
    }
    if (j < end) {
        int n0 = sorted_node[j];
        float2 v0 = reinterpret_cast<const float2*>(
                        node_feats + (size_t)n0 * HIDDEN)[lane];
        ax += v0.x; ay += v0.y;
    }

    float c = fmaxf((float)(end - start), 1.0f);
    float2 r;
    r.x = (ax + bx) / c;
    r.y = (ay + by) / c;
    reinterpret_cast<float2*>(out + (size_t)wave * HIDDEN)[lane] = r;
}

extern "C" void kernel_launch(void* const* d_in, const int* in_sizes, int n_in,
                              void* d_out, int out_size, void* d_ws, size_t ws_size,
                              hipStream_t stream) {
    const float* node_feats = (const float*)d_in[0];
    const int* he_index     = (const int*)d_in[1];
    float* out              = (float*)d_out;

    const int E      = in_sizes[1] / 2;      // 600000
    const int num_he = out_size / HIDDEN;    // 50000

    // Workspace layout (ints): counts[num_he] | offsets[num_he+1] |
    //                          cursor[num_he] | sorted_node[E]
    int* counts      = (int*)d_ws;
    int* offsets     = counts + num_he;
    int* cursor      = offsets + (num_he + 1);
    int* sorted_node = cursor + num_he;

    // Zero only the histogram (ws is poisoned 0xAA each call).
    hipMemsetAsync(counts, 0, (size_t)num_he * sizeof(int), stream);

    {
        const int threads = 256;
        const int blocks = (E + threads - 1) / threads;
        hist_kernel<<<blocks, threads, 0, stream>>>(he_index, counts, E);
    }

    scan_kernel<<<1, 1024, 0, stream>>>(counts, offsets, cursor, num_he);

    {
        const int threads = 256;
        const int blocks = (E + threads - 1) / threads;
        place_kernel<<<blocks, threads, 0, stream>>>(he_index, cursor,
                                                     sorted_node, E);
    }

    {
        const int threads = 256;                       // 4 waves per block
        const int blocks = (num_he + 3) / 4;
        aggregate_kernel<<<blocks, threads, 0, stream>>>(
            node_feats, offsets, sorted_node, out, num_he);
    }
}

// Round 4
// 203.114 us; speedup vs baseline: 5.5617x; 1.4720x over previous
//
#include <hip/hip_runtime.h>

#define HIDDEN 128
#define SCAN_B 256  // elements per scan block == threads per scan block

// ---------------------------------------------------------------------------
// Phase 1: histogram of hyperedge degrees (int atomics, L2-resident array)
// ---------------------------------------------------------------------------
__global__ void hist_kernel(const int* __restrict__ he_index,  // [2, E] flat
                            int* __restrict__ counts,          // [num_he]
                            int E) {
    int e = blockIdx.x * blockDim.x + threadIdx.x;
    if (e >= E) return;
    atomicAdd(&counts[he_index[E + e]], 1);
}

// ---------------------------------------------------------------------------
// Phase 2a: per-block partial sums of counts
// ---------------------------------------------------------------------------
__global__ void scan1_block_sums(const int* __restrict__ counts,
                                 int* __restrict__ block_sums,
                                 int num_he) {
    int i = blockIdx.x * SCAN_B + threadIdx.x;
    int v = (i < num_he) ? counts[i] : 0;

    __shared__ int lds[SCAN_B];
    lds[threadIdx.x] = v;
    __syncthreads();
    for (int off = SCAN_B / 2; off > 0; off >>= 1) {
        if (threadIdx.x < off) lds[threadIdx.x] += lds[threadIdx.x + off];
        __syncthreads();
    }
    if (threadIdx.x == 0) block_sums[blockIdx.x] = lds[0];
}

// ---------------------------------------------------------------------------
// Phase 2b: single small block scans the block sums (exclusive), writes total
// ---------------------------------------------------------------------------
__global__ void scan2_block_offsets(int* __restrict__ block_sums,  // in/out
                                    int* __restrict__ offsets,     // [num_he+1]
                                    int nblocks, int num_he) {
    __shared__ int lds[SCAN_B];
    int t = threadIdx.x;
    int v = (t < nblocks) ? block_sums[t] : 0;
    lds[t] = v;
    __syncthreads();
    for (int off = 1; off < SCAN_B; off <<= 1) {
        int tv = (t >= off) ? lds[t - off] : 0;
        __syncthreads();
        lds[t] += tv;
        __syncthreads();
    }
    if (t < nblocks) block_sums[t] = lds[t] - v;       // exclusive
    if (t == nblocks - 1) offsets[num_he] = lds[t];    // grand total = E
}

// ---------------------------------------------------------------------------
// Phase 2c: block-local exclusive scan + block offset -> offsets & cursor
// ---------------------------------------------------------------------------
__global__ void scan3_write_offsets(const int* __restrict__ counts,
                                    const int* __restrict__ block_sums,
                                    int* __restrict__ offsets,
                                    int* __restrict__ cursor,
                                    int num_he) {
    int i = blockIdx.x * SCAN_B + threadIdx.x;
    int v = (i < num_he) ? counts[i] : 0;

    __shared__ int lds[SCAN_B];
    lds[threadIdx.x] = v;
    __syncthreads();
    for (int off = 1; off < SCAN_B; off <<= 1) {
        int tv = (threadIdx.x >= off) ? lds[threadIdx.x - off] : 0;
        __syncthreads();
        lds[threadIdx.x] += tv;
        __syncthreads();
    }
    if (i < num_he) {
        int ex = lds[threadIdx.x] - v + block_sums[blockIdx.x];
        offsets[i] = ex;
        cursor[i]  = ex;
    }
}

// ---------------------------------------------------------------------------
// Phase 3: place node indices into CSR order (int atomics for slots)
// ---------------------------------------------------------------------------
__global__ void place_kernel(const int* __restrict__ he_index,   // [2, E]
                             int* __restrict__ cursor,           // [num_he]
                             int* __restrict__ sorted_node,      // [E]
                             int E) {
    int e = blockIdx.x * blockDim.x + threadIdx.x;
    if (e >= E) return;
    int node = he_index[e];
    int he   = he_index[E + e];
    int pos  = atomicAdd(&cursor[he], 1);
    sorted_node[pos] = node;
}

// ---------------------------------------------------------------------------
// Phase 4: one wave (64 lanes) per hyperedge; lane l accumulates floats
// [2l, 2l+1] across the member nodes, then writes once. No atomics.
// ---------------------------------------------------------------------------
__global__ void aggregate_kernel(const float* __restrict__ node_feats,
                                 const int* __restrict__ offsets,
                                 const int* __restrict__ sorted_node,
                                 float* __restrict__ out,
                                 int num_he) {
    int gtid = blockIdx.x * blockDim.x + threadIdx.x;
    int wave = gtid >> 6;
    int lane = threadIdx.x & 63;
    if (wave >= num_he) return;

    int start = offsets[wave];
    int end   = offsets[wave + 1];

    float ax = 0.f, ay = 0.f, bx = 0.f, by = 0.f;
    int j = start;
    for (; j + 1 < end; j += 2) {
        int n0 = sorted_node[j];
        int n1 = sorted_node[j + 1];
        float2 v0 = reinterpret_cast<const float2*>(
                        node_feats + (size_t)n0 * HIDDEN)[lane];
        float2 v1 = reinterpret_cast<const float2*>(
                        node_feats + (size_t)n1 * HIDDEN)[lane];
        ax += v0.x; ay += v0.y;
        bx += v1.x; by += v1.y;
    }
    if (j < end) {
        int n0 = sorted_node[j];
        float2 v0 = reinterpret_cast<const float2*>(
                        node_feats + (size_t)n0 * HIDDEN)[lane];
        ax += v0.x; ay += v0.y;
    }

    float c = fmaxf((float)(end - start), 1.0f);
    float2 r;
    r.x = (ax + bx) / c;
    r.y = (ay + by) / c;
    reinterpret_cast<float2*>(out + (size_t)wave * HIDDEN)[lane] = r;
}

extern "C" void kernel_launch(void* const* d_in, const int* in_sizes, int n_in,
                              void* d_out, int out_size, void* d_ws, size_t ws_size,
                              hipStream_t stream) {
    const float* node_feats = (const float*)d_in[0];
    const int* he_index     = (const int*)d_in[1];
    float* out              = (float*)d_out;

    const int E      = in_sizes[1] / 2;      // 600000
    const int num_he = out_size / HIDDEN;    // 50000
    const int nblocks_scan = (num_he + SCAN_B - 1) / SCAN_B;  // 196 (< 256)

    // Workspace layout (ints): counts[num_he] | offsets[num_he+1] |
    //   cursor[num_he] | block_sums[SCAN_B] | sorted_node[E]
    int* counts      = (int*)d_ws;
    int* offsets     = counts + num_he;
    int* cursor      = offsets + (num_he + 1);
    int* block_sums  = cursor + num_he;
    int* sorted_node = block_sums + SCAN_B;

    hipMemsetAsync(counts, 0, (size_t)num_he * sizeof(int), stream);

    {
        const int threads = 256;
        const int blocks = (E + threads - 1) / threads;
        hist_kernel<<<blocks, threads, 0, stream>>>(he_index, counts, E);
    }

    scan1_block_sums<<<nblocks_scan, SCAN_B, 0, stream>>>(counts, block_sums,
                                                          num_he);
    scan2_block_offsets<<<1, SCAN_B, 0, stream>>>(block_sums, offsets,
                                                  nblocks_scan, num_he);
    scan3_write_offsets<<<nblocks_scan, SCAN_B, 0, stream>>>(
        counts, block_sums, offsets, cursor, num_he);

    {
        const int threads = 256;
        const int blocks = (E + threads - 1) / threads;
        place_kernel<<<blocks, threads, 0, stream>>>(he_index, cursor,
                                                     sorted_node, E);
    }

    {
        const int threads = 256;                       // 4 waves per block
        const int blocks = (num_he + 3) / 4;
        aggregate_kernel<<<blocks, threads, 0, stream>>>(
            node_feats, offsets, sorted_node, out, num_he);
    }
}